// Round 7
// baseline (151.218 us; speedup 1.0000x reference)
//
#include <hip/hip_runtime.h>
#include <hip/hip_cooperative_groups.h>
#include <math.h>

namespace cg = cooperative_groups;

#define BATCH 8
#define NPRED 8192
#define MPART 2048
#define NPTS  (BATCH * NPRED)      // 65536 queries
#define MTOT  (BATCH * MPART)      // 16384 partial points
#define BASE_ALPHA 0.05f
#define EPS 1e-6f

// Grouped-SoA P': group g of 4 pts -> 4 float4: {-2x}*4, {-2y}*4, {-2z}*4, {|b|^2}*4.
// Dot is a pure 3-fma chain: d = fma(Z,az, fma(Y,ay, fma(X,ax, W))).
// near4[m] = (x,y,z,0) for single-dwordx4 nearest gathers.
__global__ __launch_bounds__(256) void prep_kernel(const float* __restrict__ partial,
                                                   float* __restrict__ ppgf,
                                                   float4* __restrict__ near4) {
    const int m = blockIdx.x * 256 + threadIdx.x;   // 64 blocks cover MTOT
    const float* p = partial + 3u * (unsigned)m;
    const float x = p[0], y = p[1], z = p[2];
    const int g = m >> 2, c = m & 3;
    float* base = ppgf + (size_t)g * 16 + c;
    base[0]  = -2.0f * x;
    base[4]  = -2.0f * y;
    base[8]  = -2.0f * z;
    base[12] = fmaf(x, x, fmaf(y, y, z * z));
    near4[m] = make_float4(x, y, z, 0.0f);
}

// ONE cooperative kernel does both refinement iterations.
// 256 blocks x 1024 threads (1 block/CU). Block qb owns queries qb*256..+255
// of batch b=qb>>5. LDS: 32 KB P' tile (whole batch, staged once, used by both
// iterations) + 32 KB key area (16 splits x 256 queries x u64).
// Wave w scans batch points [w*128, w*128+128) for all 256 queries (4/lane).
// Cross-block coupling is ONLY the per-batch max: 4 floats/block to global,
// grid.sync(), then every block reduces its batch's 128 partials.
__global__ __launch_bounds__(1024, 4) void fused_kernel(
    const float* __restrict__ pred,     // [B,N,3]
    const float4* __restrict__ ppg,     // [MTOT] grouped-SoA P'
    const float4* __restrict__ near4,   // [MTOT]
    float* __restrict__ bp1,            // [256*4] per-(block,wavegroup) max, iter 1
    float* __restrict__ bp2,            // [256*4] iter 2
    float* __restrict__ out)            // [B,N,3]
{
    cg::grid_group grid = cg::this_grid();

    __shared__ float4 tile[2048];                 // 32 KB P' (lives all kernel)
    __shared__ unsigned long long lk[4096];       // 32 KB keys (reused per iter)

    const int qb   = blockIdx.x;        // 0..255
    const int b    = qb >> 5;           // 32 blocks per batch
    const int tid  = threadIdx.x;
    const int wave = tid >> 6, lane = tid & 63;

    // Stage the batch's full P' (2048 float4), coalesced, 2 per thread.
    const float4* gsrc = ppg + (b << 11);
    tile[tid]        = gsrc[tid];
    tile[tid + 1024] = gsrc[tid + 1024];

    // Every wave holds the block's 256 queries (4 per lane) in registers.
    float ax[4], ay[4], az[4], a2[4];
    #pragma unroll
    for (int j = 0; j < 4; ++j) {
        const int t = (qb << 8) + (j << 6) + lane;
        const float* p = pred + 3u * (unsigned)t;
        ax[j] = p[0]; ay[j] = p[1]; az[j] = p[2];
        a2[j] = fmaf(ax[j], ax[j], fmaf(ay[j], ay[j], az[j] * az[j]));
    }
    __syncthreads();   // tile ready

    const float4* wp = tile + (wave << 7);   // this wave's 32 groups (128 pts)

    // Scan this wave's split for all 4 register queries; emit packed
    // (d^2, batch-index) u64 keys. Tracks h = |b|^2 - 2a.b (order == d^2);
    // group-min in loop, bit-exact rescan of the winning group in epilogue.
    auto scan_keys = [&](unsigned long long* key) {
        float best[4]; int bg[4];
        #pragma unroll
        for (int j = 0; j < 4; ++j) { best[j] = 1e30f; bg[j] = 0; }
        #pragma unroll 4
        for (int i = 0; i < 32; ++i) {
            const float4 X = wp[4 * i + 0];
            const float4 Y = wp[4 * i + 1];
            const float4 Z = wp[4 * i + 2];
            const float4 W = wp[4 * i + 3];
            #pragma unroll
            for (int j = 0; j < 4; ++j) {
                const float d0 = fmaf(Z.x, az[j], fmaf(Y.x, ay[j], fmaf(X.x, ax[j], W.x)));
                const float d1 = fmaf(Z.y, az[j], fmaf(Y.y, ay[j], fmaf(X.y, ax[j], W.y)));
                const float d2 = fmaf(Z.z, az[j], fmaf(Y.z, ay[j], fmaf(X.z, ax[j], W.z)));
                const float d3 = fmaf(Z.w, az[j], fmaf(Y.w, ay[j], fmaf(X.w, ax[j], W.w)));
                const float gm = fminf(fminf(d0, d1), fminf(d2, d3));
                if (gm < best[j]) bg[j] = i;     // strict <: earliest group wins
                best[j] = fminf(best[j], gm);
            }
        }
        #pragma unroll
        for (int j = 0; j < 4; ++j) {
            const int gi = bg[j];
            const float4 X = wp[4 * gi + 0];
            const float4 Y = wp[4 * gi + 1];
            const float4 Z = wp[4 * gi + 2];
            const float4 W = wp[4 * gi + 3];
            const float d0 = fmaf(Z.x, az[j], fmaf(Y.x, ay[j], fmaf(X.x, ax[j], W.x)));
            const float d1 = fmaf(Z.y, az[j], fmaf(Y.y, ay[j], fmaf(X.y, ax[j], W.y)));
            const float d2 = fmaf(Z.z, az[j], fmaf(Y.z, ay[j], fmaf(X.z, ax[j], W.z)));
            const float bv = best[j];
            int c;
            if      (d0 == bv) c = 0;            // fminf returns an operand exactly
            else if (d1 == bv) c = 1;
            else if (d2 == bv) c = 2;
            else               c = 3;
            const int m = (wave << 7) + (gi << 2) + c;      // index within batch
            const float dd = fmaxf(bv + a2[j], 0.0f);       // nonneg -> uint-ordered
            key[j] = ((unsigned long long)__float_as_uint(dd) << 32) | (unsigned)m;
        }
    };

    // ======================= iteration 1 =======================
    unsigned long long key1[4];
    scan_keys(key1);
    #pragma unroll
    for (int j = 0; j < 4; ++j)
        lk[(wave << 8) + (j << 6) + lane] = key1[j];
    __syncthreads();

    // Merge 16 splits (u64 min == (d^2, first-index) lex); thread tid<256
    // exclusively owns column tid. Then per-wave max -> 4 global partials.
    if (tid < 256) {
        unsigned long long kk = lk[tid];
        #pragma unroll
        for (int s = 1; s < 16; ++s) {
            const unsigned long long k = lk[(s << 8) + tid];
            if (k < kk) kk = k;
        }
        lk[tid] = kk;                            // safe: only thread tid touches col tid
        float w = sqrtf(__uint_as_float((unsigned)(kk >> 32)));
        #pragma unroll
        for (int o = 32; o > 0; o >>= 1) w = fmaxf(w, __shfl_down(w, o, 64));
        if (lane == 0) bp1[(qb << 2) + wave] = w;
    }
    grid.sync();   // includes block barrier + device-scope ordering

    // Batch max (128 partials, contiguous), computed redundantly per wave.
    {
        float v = fmaxf(bp1[(b << 7) + lane], bp1[(b << 7) + 64 + lane]);
        #pragma unroll
        for (int o = 32; o > 0; o >>= 1) v = fmaxf(v, __shfl_down(v, o, 64));
        const float maxv = __shfl(v, 0, 64);

        // Iter-1 blend applied to the register copies (all waves identically).
        #pragma unroll
        for (int j = 0; j < 4; ++j) {
            const int q = (j << 6) + lane;
            const unsigned long long kk = lk[q];
            const float md = sqrtf(__uint_as_float((unsigned)(kk >> 32)));
            const int   id = (int)(kk & 0xffffffffu);
            const float alpha = BASE_ALPHA * (2.0f - md / (maxv + EPS));
            const float4 nb = near4[(b << 11) + id];
            ax[j] = fmaf(alpha, nb.x - ax[j], ax[j]);
            ay[j] = fmaf(alpha, nb.y - ay[j], ay[j]);
            az[j] = fmaf(alpha, nb.z - az[j], az[j]);
            a2[j] = fmaf(ax[j], ax[j], fmaf(ay[j], ay[j], az[j] * az[j]));
        }
    }
    __syncthreads();   // all lk reads done before iteration 2 overwrites

    // ======================= iteration 2 =======================
    unsigned long long key2[4];
    scan_keys(key2);
    #pragma unroll
    for (int j = 0; j < 4; ++j)
        lk[(wave << 8) + (j << 6) + lane] = key2[j];
    __syncthreads();

    float md2 = 0.0f; int idx2 = 0;
    if (tid < 256) {
        unsigned long long kk = lk[tid];
        #pragma unroll
        for (int s = 1; s < 16; ++s) {
            const unsigned long long k = lk[(s << 8) + tid];
            if (k < kk) kk = k;
        }
        md2  = sqrtf(__uint_as_float((unsigned)(kk >> 32)));
        idx2 = (int)(kk & 0xffffffffu);
        float w = md2;
        #pragma unroll
        for (int o = 32; o > 0; o >>= 1) w = fmaxf(w, __shfl_down(w, o, 64));
        if (lane == 0) bp2[(qb << 2) + wave] = w;
    }
    grid.sync();

    // Final blend + output. Thread tid<256 owns query tid; its iter-1 position
    // sits in register slot j==wave (since (wave<<6)+lane == tid for tid<256).
    if (tid < 256) {
        float v = fmaxf(bp2[(b << 7) + lane], bp2[(b << 7) + 64 + lane]);
        #pragma unroll
        for (int o = 32; o > 0; o >>= 1) v = fmaxf(v, __shfl_down(v, o, 64));
        const float maxv = __shfl(v, 0, 64);
        const float alpha = BASE_ALPHA * (2.0f - md2 / (maxv + EPS));
        const float4 nb = near4[(b << 11) + idx2];
        const int j = wave;
        const float px = ax[j], py = ay[j], pz = az[j];
        float* o = out + 3u * (unsigned)((qb << 8) + tid);
        o[0] = fmaf(alpha, nb.x - px, px);
        o[1] = fmaf(alpha, nb.y - py, py);
        o[2] = fmaf(alpha, nb.z - pz, pz);
    }
}

extern "C" void kernel_launch(void* const* d_in, const int* in_sizes, int n_in,
                              void* d_out, int out_size, void* d_ws, size_t ws_size,
                              hipStream_t stream) {
    const float* pred    = (const float*)d_in[0];   // [8,8192,3] fp32
    const float* partial = (const float*)d_in[1];   // [8,2048,3] fp32
    float* out = (float*)d_out;

    char* ws = (char*)d_ws;
    float4* ppg   = (float4*)ws;                    // 256 KB grouped-SoA P'
    float4* near4 = (float4*)(ws + 262144);         // 256 KB
    float*  bp1   = (float*)(ws + 524288);          // 4 KB per-block max partials
    float*  bp2   = (float*)(ws + 528384);          // 4 KB

    prep_kernel<<<MTOT / 256, 256, 0, stream>>>(partial, (float*)ppg, near4);

    void* args[] = { (void*)&pred, (void*)&ppg, (void*)&near4,
                     (void*)&bp1, (void*)&bp2, (void*)&out };
    hipLaunchCooperativeKernel((void*)fused_kernel, dim3(256), dim3(1024),
                               args, 0, stream);
}